// Round 2
// baseline (4540.303 us; speedup 1.0000x reference)
//
#include <hip/hip_runtime.h>
#include <math.h>

#define NN   65536
#define EE   32768
#define HH   256
#define KK   24
#define DDIM 1280
#define OUTD 512

#define BM 128
#define BN 128
#define BK 16
#define TM 8
#define TN 8

__device__ __forceinline__ float elu1(float x) {
    return x > 0.f ? x : expm1f(x);
}

// One block (256 threads) per edge (within a chunk). Thread t owns channel t.
// src_idx/dst_idx/sl/sr/elem/emb/stat are pre-offset to the chunk base.
__global__ __launch_bounds__(256) void feats_kernel(
    const float* __restrict__ X,
    const int* __restrict__ src_idx, const int* __restrict__ dst_idx,
    const int* __restrict__ batch_vec, const int* __restrict__ ptrv,
    const int* __restrict__ sl, const int* __restrict__ sr,
    const float* __restrict__ elem, const float* __restrict__ emb,
    const float* __restrict__ stat, float* __restrict__ F)
{
    const int e = blockIdx.x;          // local edge id within chunk
    const int t = threadIdx.x;
    const int src = src_idx[e];
    const int dst = dst_idx[e];
    const int off = ptrv[batch_vec[src]];
    float* f = F + (size_t)e * DDIM;

    // node_pairs
    f[t]      = X[(size_t)src * HH + t];
    f[HH + t] = X[(size_t)dst * HH + t];

    // masked segment-mean pools. Mask applies AFTER the ptr offset (matches
    // reference): flat == -1 only masks padding in graph 0; for graph g>0 a
    // padding -1 becomes g*1024-1 and IS gathered+counted.
    float sL = 0.f, sR = 0.f;
    int cL = 0, cR = 0;
    #pragma unroll
    for (int k = 0; k < KK; ++k) {
        const int il = sl[e * KK + k] + off;
        if (il != -1) { sL += X[(size_t)il * HH + t]; cL++; }
        const int ir = sr[e * KK + k] + off;
        if (ir != -1) { sR += X[(size_t)ir * HH + t]; cR++; }
    }
    f[2 * HH + t] = (cL > 0) ? sL / (float)cL : 0.f;
    f[3 * HH + t] = (cR > 0) ? sR / (float)cR : 0.f;

    // tail features
    if (t < 24)  f[1024 + t] = elem[e * 24 + t];
    if (t < 200) f[1048 + t] = emb[e * 200 + t];
    if (t < 32)  f[1248 + t] = stat[e * 32 + t];
}

// C[M,N] = act(A[M,K] @ W[K,N] + bias) (+ A residual when RESID).
// 128x128 block tile, BK=16, 8x8 per thread, 256 threads.
template<bool RESID>
__global__ __launch_bounds__(256) void gemm_bias_kernel(
    const float* __restrict__ A, const float* __restrict__ W,
    const float* __restrict__ bias, float* __restrict__ C,
    int M, int N, int K)
{
    __shared__ float As[BK][BM + 4];   // transposed: As[k][m]
    __shared__ float Bs[BK][BN + 4];

    const int t  = threadIdx.x;
    const int m0 = blockIdx.y * BM;
    const int n0 = blockIdx.x * BN;
    const int ty = t >> 4;
    const int tx = t & 15;
    const int arow = t >> 2;
    const int acol = (t & 3) << 2;
    const int brow = t >> 5;
    const int bcol = (t & 31) << 2;

    float acc[TM][TN];
    #pragma unroll
    for (int i = 0; i < TM; ++i)
        #pragma unroll
        for (int j = 0; j < TN; ++j) acc[i][j] = 0.f;

    for (int k0 = 0; k0 < K; k0 += BK) {
        const float4 a0 = *(const float4*)(A + (size_t)(m0 + arow) * K + k0 + acol);
        const float4 a1 = *(const float4*)(A + (size_t)(m0 + arow + 64) * K + k0 + acol);
        const float4 b0 = *(const float4*)(W + (size_t)(k0 + brow) * N + n0 + bcol);
        const float4 b1 = *(const float4*)(W + (size_t)(k0 + brow + 8) * N + n0 + bcol);

        __syncthreads();

        As[acol + 0][arow] = a0.x;
        As[acol + 1][arow] = a0.y;
        As[acol + 2][arow] = a0.z;
        As[acol + 3][arow] = a0.w;
        As[acol + 0][arow + 64] = a1.x;
        As[acol + 1][arow + 64] = a1.y;
        As[acol + 2][arow + 64] = a1.z;
        As[acol + 3][arow + 64] = a1.w;
        *(float4*)&Bs[brow][bcol]     = b0;
        *(float4*)&Bs[brow + 8][bcol] = b1;

        __syncthreads();

        #pragma unroll
        for (int k = 0; k < BK; ++k) {
            const float4 av0 = *(const float4*)&As[k][ty * TM];
            const float4 av1 = *(const float4*)&As[k][ty * TM + 4];
            const float4 bv0 = *(const float4*)&Bs[k][tx * TN];
            const float4 bv1 = *(const float4*)&Bs[k][tx * TN + 4];
            const float a[TM] = {av0.x, av0.y, av0.z, av0.w, av1.x, av1.y, av1.z, av1.w};
            const float b[TN] = {bv0.x, bv0.y, bv0.z, bv0.w, bv1.x, bv1.y, bv1.z, bv1.w};
            #pragma unroll
            for (int i = 0; i < TM; ++i)
                #pragma unroll
                for (int j = 0; j < TN; ++j)
                    acc[i][j] += a[i] * b[j];
        }
    }

    float bias_v[TN];
    #pragma unroll
    for (int j = 0; j < TN; ++j) bias_v[j] = bias[n0 + tx * TN + j];

    #pragma unroll
    for (int i = 0; i < TM; ++i) {
        const int m = m0 + ty * TM + i;
        float out_v[TN];
        if (RESID) {
            #pragma unroll
            for (int j = 0; j < TN; ++j) {
                const float h = A[(size_t)m * K + n0 + tx * TN + j];
                out_v[j] = elu1(acc[i][j] + bias_v[j]) + h;
            }
        } else {
            #pragma unroll
            for (int j = 0; j < TN; ++j)
                out_v[j] = acc[i][j] + bias_v[j];
        }
        *(float4*)(C + (size_t)m * N + n0 + tx * TN)     = make_float4(out_v[0], out_v[1], out_v[2], out_v[3]);
        *(float4*)(C + (size_t)m * N + n0 + tx * TN + 4) = make_float4(out_v[4], out_v[5], out_v[6], out_v[7]);
    }
}

extern "C" void kernel_launch(void* const* d_in, const int* in_sizes, int n_in,
                              void* d_out, int out_size, void* d_ws, size_t ws_size,
                              hipStream_t stream) {
    const float* X          = (const float*)d_in[0];
    const int*   edge_index = (const int*)d_in[1];
    const int*   batch_vec  = (const int*)d_in[2];
    const int*   ptrv       = (const int*)d_in[3];
    const int*   sl         = (const int*)d_in[4];
    const int*   sr         = (const int*)d_in[5];
    const float* elem       = (const float*)d_in[6];
    const float* emb        = (const float*)d_in[7];
    const float* stat       = (const float*)d_in[8];
    const float* Wd         = (const float*)d_in[9];
    const float* bd         = (const float*)d_in[10];
    const float* Wo         = (const float*)d_in[11];
    const float* bo         = (const float*)d_in[12];
    float* out  = (float*)d_out;

    // Adaptive chunking: largest CH (multiple of BM, halving from EE) whose
    // two ping-pong h buffers (CH x DDIM floats each) fit in ws_size.
    int CH = EE;
    while (CH > BM && (size_t)2 * (size_t)CH * DDIM * sizeof(float) > ws_size)
        CH >>= 1;

    float* buf0 = (float*)d_ws;
    float* buf1 = buf0 + (size_t)CH * DDIM;

    for (int e0 = 0; e0 < EE; e0 += CH) {
        // 1) assemble features for this chunk into buf0
        feats_kernel<<<CH, 256, 0, stream>>>(
            X, edge_index + e0, edge_index + EE + e0, batch_vec, ptrv,
            sl + (size_t)e0 * KK, sr + (size_t)e0 * KK,
            elem + (size_t)e0 * 24, emb + (size_t)e0 * 200,
            stat + (size_t)e0 * 32, buf0);

        // 2) three residual dense layers (ping-pong within chunk)
        dim3 gd(DDIM / BN, CH / BM);
        gemm_bias_kernel<true><<<gd, 256, 0, stream>>>(
            buf0, Wd + 0 * (size_t)DDIM * DDIM, bd + 0 * DDIM, buf1, CH, DDIM, DDIM);
        gemm_bias_kernel<true><<<gd, 256, 0, stream>>>(
            buf1, Wd + 1 * (size_t)DDIM * DDIM, bd + 1 * DDIM, buf0, CH, DDIM, DDIM);
        gemm_bias_kernel<true><<<gd, 256, 0, stream>>>(
            buf0, Wd + 2 * (size_t)DDIM * DDIM, bd + 2 * DDIM, buf1, CH, DDIM, DDIM);

        // 3) output projection straight into d_out
        dim3 go(OUTD / BN, CH / BM);
        gemm_bias_kernel<false><<<go, 256, 0, stream>>>(
            buf1, Wo, bo, out + (size_t)e0 * OUTD, CH, OUTD, DDIM);
    }
}

// Round 4
// 1291.542 us; speedup vs baseline: 3.5154x; 3.5154x over previous
//
#include <hip/hip_runtime.h>
#include <math.h>

#define NN   65536
#define EE   32768
#define HH   256
#define KK   24
#define DDIM 1280
#define OUTD 512
#define KT   (DDIM / 32)   // 40 K-steps of 32

typedef _Float16 half8 __attribute__((ext_vector_type(8)));
typedef float    f32x4 __attribute__((ext_vector_type(4)));

__device__ __forceinline__ float elu1(float x) {
    return x > 0.f ? x : expm1f(x);
}

// ---------------------------------------------------------------------------
// Weight conversion: fp32 row-major W[K][N] -> fp16 fragment-major subtiles.
// Subtile s = (kt*nbN + nb)*8 + nt covers rows kt*32..+31, cols nb*128+nt*16..+15.
// Within a subtile: lane l (0..63) holds B[k = 8*(l>>4)+j][n = l&15], j=0..7,
// stored as 64 contiguous 16B chunks (1 KiB) -> frag load is ds_read_b128 at
// base + lane*16 (conflict-free, matches mfma_f32_16x16x32 B-operand layout).
// ---------------------------------------------------------------------------
__global__ __launch_bounds__(256) void wconv_kernel(
    const float* __restrict__ W, _Float16* __restrict__ W16, int N, int nbN)
{
    const int t    = threadIdx.x;
    const int s    = blockIdx.x * 4 + (t >> 6);
    const int lane = t & 63;
    const int nt = s & 7;
    const int nb = (s >> 3) % nbN;
    const int kt = s / (8 * nbN);
    const int kbase = kt * 32 + 8 * (lane >> 4);
    const int n     = nb * 128 + nt * 16 + (lane & 15);
    half8 v;
    #pragma unroll
    for (int j = 0; j < 8; ++j)
        v[j] = (_Float16)W[(size_t)(kbase + j) * N + n];
    *((half8*)W16 + (size_t)s * 64 + lane) = v;
}

// ---------------------------------------------------------------------------
// Feature assembly: one wave (64 lanes) per edge, float4 per lane (H=256).
// ---------------------------------------------------------------------------
__global__ __launch_bounds__(256) void feats4_kernel(
    const float* __restrict__ X,
    const int* __restrict__ src_idx, const int* __restrict__ dst_idx,
    const int* __restrict__ batch_vec, const int* __restrict__ ptrv,
    const int* __restrict__ sl, const int* __restrict__ sr,
    const float* __restrict__ elem, const float* __restrict__ emb,
    const float* __restrict__ stat, float* __restrict__ F)
{
    const int lane = threadIdx.x & 63;
    const int e    = blockIdx.x * 4 + (threadIdx.x >> 6);
    const int src  = src_idx[e];
    const int dst  = dst_idx[e];
    const int off  = ptrv[batch_vec[src]];

    const float4* X4 = (const float4*)X;
    float4* f4 = (float4*)(F + (size_t)e * DDIM);

    f4[lane]      = X4[(size_t)src * 64 + lane];
    f4[64 + lane] = X4[(size_t)dst * 64 + lane];

    // masked segment-mean pools; mask applies AFTER ptr offset (reference
    // semantics: -1 padding only masked for graph 0, g>0 wraps to g*1024-1).
    float4 sL = make_float4(0.f, 0.f, 0.f, 0.f);
    float4 sR = make_float4(0.f, 0.f, 0.f, 0.f);
    int cL = 0, cR = 0;
    #pragma unroll
    for (int k = 0; k < KK; ++k) {
        const int il = sl[e * KK + k] + off;
        if (il != -1) {
            const float4 v = X4[(size_t)il * 64 + lane];
            sL.x += v.x; sL.y += v.y; sL.z += v.z; sL.w += v.w; cL++;
        }
        const int ir = sr[e * KK + k] + off;
        if (ir != -1) {
            const float4 v = X4[(size_t)ir * 64 + lane];
            sR.x += v.x; sR.y += v.y; sR.z += v.z; sR.w += v.w; cR++;
        }
    }
    const float rL = cL > 0 ? 1.f / (float)cL : 0.f;
    const float rR = cR > 0 ? 1.f / (float)cR : 0.f;
    f4[128 + lane] = make_float4(sL.x * rL, sL.y * rL, sL.z * rL, sL.w * rL);
    f4[192 + lane] = make_float4(sR.x * rR, sR.y * rR, sR.z * rR, sR.w * rR);

    // tail features: 24 + 200 + 32 floats = 64 float4 exactly
    if (lane < 6)       f4[256 + lane] = ((const float4*)(elem + (size_t)e * 24))[lane];
    else if (lane < 56) f4[256 + lane] = ((const float4*)(emb  + (size_t)e * 200))[lane - 6];
    else                f4[256 + lane] = ((const float4*)(stat + (size_t)e * 32))[lane - 56];
}

// ---------------------------------------------------------------------------
// MFMA GEMM: C[M,N] = act(A_f32[M,1280] @ W16 + bias) (+A residual if RESID).
// 128x128 block tile, BK=32, 4 waves, mfma_f32_16x16x32_f16, fp32 accum.
// A is converted fp32->fp16 during LDS staging; W16 is fragment-major (above).
// ---------------------------------------------------------------------------
template<bool RESID>
__global__ __launch_bounds__(256) void mfma_gemm_kernel(
    const float* __restrict__ A, const _Float16* __restrict__ W16,
    const float* __restrict__ bias, float* __restrict__ C,
    int N, int nbN)
{
    __shared__ __align__(16) char sA[8192];   // 8 subtiles (m), fragment-major
    __shared__ __align__(16) char sB[8192];   // 8 subtiles (n), fragment-major

    const int t    = threadIdx.x;
    const int wid  = t >> 6;
    const int lane = t & 63;
    const int m0   = blockIdx.y * 128;
    const int n0b  = blockIdx.x;              // n-block index

    f32x4 acc[2][8];
    #pragma unroll
    for (int i = 0; i < 2; ++i)
        #pragma unroll
        for (int j = 0; j < 8; ++j)
            acc[i][j] = (f32x4){0.f, 0.f, 0.f, 0.f};

    // A staging assignment: thread t -> row ar = t>>1, k-half akh = (t&1)*16
    const int ar  = t >> 1;
    const int akh = (t & 1) * 16;
    const float* Ag = A + (size_t)(m0 + ar) * DDIM + akh;
    char* aw = sA + ((ar >> 4) * 1024) + (((ar & 15) + 2 * akh) * 16); // lane=(ar&15)+32*(t&1)

    // B staging assignment: thread t copies 32B of subtile bs
    const int bs    = t >> 5;
    const int bslot = t & 31;
    const char* W16b = (const char*)W16;
    char* bw = sB + bs * 1024 + bslot * 32;

    float4 a0, a1, a2, a3;
    uint4  b0, b1;

#define LOADG(ktv)                                                              \
    {                                                                           \
        const float4* ap = (const float4*)(Ag + (size_t)(ktv) * 32);            \
        a0 = ap[0]; a1 = ap[1]; a2 = ap[2]; a3 = ap[3];                         \
        const uint4* bp = (const uint4*)(W16b +                                 \
            ((size_t)((ktv) * nbN + n0b) * 8 + bs) * 1024 + bslot * 32);        \
        b0 = bp[0]; b1 = bp[1];                                                 \
    }

    LOADG(0);

    for (int kt = 0; kt < KT; ++kt) {
        __syncthreads();   // previous step's compute done before LDS overwrite

        half8 h0, h1;
        h0[0]=(_Float16)a0.x; h0[1]=(_Float16)a0.y; h0[2]=(_Float16)a0.z; h0[3]=(_Float16)a0.w;
        h0[4]=(_Float16)a1.x; h0[5]=(_Float16)a1.y; h0[6]=(_Float16)a1.z; h0[7]=(_Float16)a1.w;
        h1[0]=(_Float16)a2.x; h1[1]=(_Float16)a2.y; h1[2]=(_Float16)a2.z; h1[3]=(_Float16)a2.w;
        h1[4]=(_Float16)a3.x; h1[5]=(_Float16)a3.y; h1[6]=(_Float16)a3.z; h1[7]=(_Float16)a3.w;
        *(half8*)aw         = h0;
        *(half8*)(aw + 256) = h1;
        *(uint4*)bw        = b0;
        *(uint4*)(bw + 16) = b1;

        __syncthreads();

        if (kt + 1 < KT) LOADG(kt + 1);   // overlap next loads with MFMA

        const half8* pa = (const half8*)sA;
        const half8* pb = (const half8*)sB;
        const half8 af0 = pa[(2 * wid)     * 64 + lane];
        const half8 af1 = pa[(2 * wid + 1) * 64 + lane];
        #pragma unroll
        for (int j = 0; j < 8; ++j) {
            const half8 bf = pb[j * 64 + lane];
            acc[0][j] = __builtin_amdgcn_mfma_f32_16x16x32_f16(af0, bf, acc[0][j], 0, 0, 0);
            acc[1][j] = __builtin_amdgcn_mfma_f32_16x16x32_f16(af1, bf, acc[1][j], 0, 0, 0);
        }
    }
#undef LOADG

    // Epilogue. D layout (verified m89): col = lane&15, row = (lane>>4)*4 + r.
    #pragma unroll
    for (int i = 0; i < 2; ++i) {
        const int rbase = m0 + wid * 32 + i * 16 + (lane >> 4) * 4;
        #pragma unroll
        for (int j = 0; j < 8; ++j) {
            const int col = n0b * 128 + j * 16 + (lane & 15);
            const float bv = bias[col];
            #pragma unroll
            for (int r = 0; r < 4; ++r) {
                const int row = rbase + r;
                float v = acc[i][j][r] + bv;
                if (RESID) v = elu1(v) + A[(size_t)row * DDIM + col];
                C[(size_t)row * N + col] = v;
            }
        }
    }
}

extern "C" void kernel_launch(void* const* d_in, const int* in_sizes, int n_in,
                              void* d_out, int out_size, void* d_ws, size_t ws_size,
                              hipStream_t stream) {
    const float* X          = (const float*)d_in[0];
    const int*   edge_index = (const int*)d_in[1];
    const int*   batch_vec  = (const int*)d_in[2];
    const int*   ptrv       = (const int*)d_in[3];
    const int*   sl         = (const int*)d_in[4];
    const int*   sr         = (const int*)d_in[5];
    const float* elem       = (const float*)d_in[6];
    const float* emb        = (const float*)d_in[7];
    const float* stat       = (const float*)d_in[8];
    const float* Wd         = (const float*)d_in[9];
    const float* bd         = (const float*)d_in[10];
    const float* Wo         = (const float*)d_in[11];
    const float* bo         = (const float*)d_in[12];
    float* out = (float*)d_out;

    // ws layout: [W16 square x3 | W16 out | h ping-pong buffers]
    const size_t LW  = (size_t)KT * 10 * 8 * 1024;   // 3,276,800 B per square layer
    const size_t LWo = (size_t)KT * 4  * 8 * 1024;   // 1,310,720 B
    _Float16* W16d = (_Float16*)d_ws;
    _Float16* W16o = (_Float16*)((char*)d_ws + 3 * LW);
    char* hbase = (char*)d_ws + 3 * LW + LWo;
    const size_t rem = ws_size - (3 * LW + LWo);

    int CH = EE;
    while (CH > 128 && (size_t)2 * CH * DDIM * sizeof(float) > rem) CH >>= 1;
    float* buf0 = (float*)hbase;
    float* buf1 = buf0 + (size_t)CH * DDIM;

    // one-time (per launch) weight conversion to fp16 fragment-major tiles
    for (int l = 0; l < 3; ++l)
        wconv_kernel<<<800, 256, 0, stream>>>(
            Wd + (size_t)l * DDIM * DDIM, W16d + (size_t)l * (LW / 2), DDIM, 10);
    wconv_kernel<<<320, 256, 0, stream>>>(Wo, W16o, OUTD, 4);

    for (int e0 = 0; e0 < EE; e0 += CH) {
        feats4_kernel<<<CH / 4, 256, 0, stream>>>(
            X, edge_index + e0, edge_index + EE + e0, batch_vec, ptrv,
            sl + (size_t)e0 * KK, sr + (size_t)e0 * KK,
            elem + (size_t)e0 * 24, emb + (size_t)e0 * 200,
            stat + (size_t)e0 * 32, buf0);

        dim3 gd(10, CH / 128);
        mfma_gemm_kernel<true><<<gd, 256, 0, stream>>>(
            buf0, W16d + 0 * (LW / 2), bd + 0 * DDIM, buf1, DDIM, 10);
        mfma_gemm_kernel<true><<<gd, 256, 0, stream>>>(
            buf1, W16d + 1 * (LW / 2), bd + 1 * DDIM, buf0, DDIM, 10);
        mfma_gemm_kernel<true><<<gd, 256, 0, stream>>>(
            buf0, W16d + 2 * (LW / 2), bd + 2 * DDIM, buf1, DDIM, 10);

        dim3 go(4, CH / 128);
        mfma_gemm_kernel<false><<<go, 256, 0, stream>>>(
            buf1, W16o, bo, out + (size_t)e0 * OUTD, OUTD, 4);
    }
}

// Round 5
// 1138.440 us; speedup vs baseline: 3.9882x; 1.1345x over previous
//
#include <hip/hip_runtime.h>
#include <math.h>

#define NN   65536
#define EE   32768
#define HH   256
#define KK   24
#define DDIM 1280
#define OUTD 512
#define KT   (DDIM / 32)   // 40 K-steps of 32

typedef _Float16 half8 __attribute__((ext_vector_type(8)));
typedef float    f32x4 __attribute__((ext_vector_type(4)));

__device__ __forceinline__ float elu1(float x) {
    return x > 0.f ? x : expm1f(x);
}

// ---------------------------------------------------------------------------
// Weight conversion: fp32 row-major W[K][N] -> fp16 fragment-major subtiles.
// Subtile s = (kt*nbN + nb)*8 + nt covers rows kt*32..+31, cols nb*128+nt*16..+15.
// Lane l holds B[k = 8*(l>>4)+j][n = l&15], j=0..7, as 64 contiguous 16B chunks.
// ---------------------------------------------------------------------------
__global__ __launch_bounds__(256) void wconv_kernel(
    const float* __restrict__ W, _Float16* __restrict__ W16, int N, int nbN)
{
    const int t    = threadIdx.x;
    const int s    = blockIdx.x * 4 + (t >> 6);
    const int lane = t & 63;
    const int nt = s & 7;
    const int nb = (s >> 3) % nbN;
    const int kt = s / (8 * nbN);
    const int kbase = kt * 32 + 8 * (lane >> 4);
    const int n     = nb * 128 + nt * 16 + (lane & 15);
    half8 v;
    #pragma unroll
    for (int j = 0; j < 8; ++j)
        v[j] = (_Float16)W[(size_t)(kbase + j) * N + n];
    *((half8*)W16 + (size_t)s * 64 + lane) = v;
}

// ---------------------------------------------------------------------------
// Feature assembly: one wave per edge, float4 per lane. BRANCHLESS pooling:
// il >= -1 always (off >= 0, sl >= -1), and the reference masks AFTER the
// offset, so il == -1 (<0) is the only masked case. Clamp index to 0 and
// weight by 0/1 -> all 48 gathers are unconditional and issue back-to-back.
// ---------------------------------------------------------------------------
__global__ __launch_bounds__(256) void feats4_kernel(
    const float* __restrict__ X,
    const int* __restrict__ src_idx, const int* __restrict__ dst_idx,
    const int* __restrict__ batch_vec, const int* __restrict__ ptrv,
    const int* __restrict__ sl, const int* __restrict__ sr,
    const float* __restrict__ elem, const float* __restrict__ emb,
    const float* __restrict__ stat, float* __restrict__ F)
{
    const int lane = threadIdx.x & 63;
    const int e    = blockIdx.x * 4 + (threadIdx.x >> 6);
    const int src  = src_idx[e];
    const int dst  = dst_idx[e];
    const int off  = ptrv[batch_vec[src]];

    const float4* X4 = (const float4*)X;
    float4* f4 = (float4*)(F + (size_t)e * DDIM);

    f4[lane]      = X4[(size_t)src * 64 + lane];
    f4[64 + lane] = X4[(size_t)dst * 64 + lane];

    float4 sL = make_float4(0.f, 0.f, 0.f, 0.f);
    float4 sR = make_float4(0.f, 0.f, 0.f, 0.f);
    int cL = 0, cR = 0;
    #pragma unroll
    for (int k = 0; k < KK; ++k) {
        const int il  = sl[e * KK + k] + off;
        const int ir  = sr[e * KK + k] + off;
        const int okL = il >= 0;
        const int okR = ir >= 0;
        const float wL = okL ? 1.f : 0.f;
        const float wR = okR ? 1.f : 0.f;
        const float4 vl = X4[(size_t)(okL ? il : 0) * 64 + lane];
        const float4 vr = X4[(size_t)(okR ? ir : 0) * 64 + lane];
        sL.x += vl.x * wL; sL.y += vl.y * wL; sL.z += vl.z * wL; sL.w += vl.w * wL;
        sR.x += vr.x * wR; sR.y += vr.y * wR; sR.z += vr.z * wR; sR.w += vr.w * wR;
        cL += okL; cR += okR;
    }
    const float rL = cL > 0 ? 1.f / (float)cL : 0.f;
    const float rR = cR > 0 ? 1.f / (float)cR : 0.f;
    f4[128 + lane] = make_float4(sL.x * rL, sL.y * rL, sL.z * rL, sL.w * rL);
    f4[192 + lane] = make_float4(sR.x * rR, sR.y * rR, sR.z * rR, sR.w * rR);

    // tail features: 24 + 200 + 32 floats = 64 float4 exactly
    if (lane < 6)       f4[256 + lane] = ((const float4*)(elem + (size_t)e * 24))[lane];
    else if (lane < 56) f4[256 + lane] = ((const float4*)(emb  + (size_t)e * 200))[lane - 6];
    else                f4[256 + lane] = ((const float4*)(stat + (size_t)e * 32))[lane - 56];
}

// ---------------------------------------------------------------------------
// MFMA GEMM: C[M,N] = act(A_f32[M,1280] @ W16 + bias) (+A residual if RESID).
// 128x128 tile, BK=32, 4 waves, mfma_f32_16x16x32_f16, fp32 accum.
// XCD-affinity swizzle: all n-blocks of one m-tile get flat ids congruent
// mod 8 -> same XCD (round-robin dispatch) -> A panel (655 KB) stays in that
// XCD's 4 MB L2 for both staging and the residual re-read.
// ---------------------------------------------------------------------------
template<bool RESID>
__global__ __launch_bounds__(256) void mfma_gemm_kernel(
    const float* __restrict__ A, const _Float16* __restrict__ W16,
    const float* __restrict__ bias, float* __restrict__ C,
    int N, int nbN)
{
    __shared__ __align__(16) char sA[8192];
    __shared__ __align__(16) char sB[8192];

    const int t    = threadIdx.x;
    const int wid  = t >> 6;
    const int lane = t & 63;

    int m_t, n_t;
    if ((gridDim.y & 7) == 0) {
        const int flat = blockIdx.y * gridDim.x + blockIdx.x;
        m_t = (flat & 7) + 8 * (flat / (8 * gridDim.x));
        n_t = (flat >> 3) % gridDim.x;
    } else {
        m_t = blockIdx.y;
        n_t = blockIdx.x;
    }
    const int m0  = m_t * 128;
    const int n0b = n_t;

    f32x4 acc[2][8];
    #pragma unroll
    for (int i = 0; i < 2; ++i)
        #pragma unroll
        for (int j = 0; j < 8; ++j)
            acc[i][j] = (f32x4){0.f, 0.f, 0.f, 0.f};

    const int ar  = t >> 1;
    const int akh = (t & 1) * 16;
    const float* Ag = A + (size_t)(m0 + ar) * DDIM + akh;
    char* aw = sA + ((ar >> 4) * 1024) + (((ar & 15) + 2 * akh) * 16);

    const int bs    = t >> 5;
    const int bslot = t & 31;
    const char* W16b = (const char*)W16;
    char* bw = sB + bs * 1024 + bslot * 32;

    float4 a0, a1, a2, a3;
    uint4  b0, b1;

#define LOADG(ktv)                                                              \
    {                                                                           \
        const float4* ap = (const float4*)(Ag + (size_t)(ktv) * 32);            \
        a0 = ap[0]; a1 = ap[1]; a2 = ap[2]; a3 = ap[3];                         \
        const uint4* bp = (const uint4*)(W16b +                                 \
            ((size_t)((ktv) * nbN + n0b) * 8 + bs) * 1024 + bslot * 32);        \
        b0 = bp[0]; b1 = bp[1];                                                 \
    }

    LOADG(0);

    for (int kt = 0; kt < KT; ++kt) {
        __syncthreads();

        half8 h0, h1;
        h0[0]=(_Float16)a0.x; h0[1]=(_Float16)a0.y; h0[2]=(_Float16)a0.z; h0[3]=(_Float16)a0.w;
        h0[4]=(_Float16)a1.x; h0[5]=(_Float16)a1.y; h0[6]=(_Float16)a1.z; h0[7]=(_Float16)a1.w;
        h1[0]=(_Float16)a2.x; h1[1]=(_Float16)a2.y; h1[2]=(_Float16)a2.z; h1[3]=(_Float16)a2.w;
        h1[4]=(_Float16)a3.x; h1[5]=(_Float16)a3.y; h1[6]=(_Float16)a3.z; h1[7]=(_Float16)a3.w;
        *(half8*)aw         = h0;
        *(half8*)(aw + 256) = h1;
        *(uint4*)bw        = b0;
        *(uint4*)(bw + 16) = b1;

        __syncthreads();

        if (kt + 1 < KT) LOADG(kt + 1);

        const half8* pa = (const half8*)sA;
        const half8* pb = (const half8*)sB;
        const half8 af0 = pa[(2 * wid)     * 64 + lane];
        const half8 af1 = pa[(2 * wid + 1) * 64 + lane];
        #pragma unroll
        for (int j = 0; j < 8; ++j) {
            const half8 bf = pb[j * 64 + lane];
            acc[0][j] = __builtin_amdgcn_mfma_f32_16x16x32_f16(af0, bf, acc[0][j], 0, 0, 0);
            acc[1][j] = __builtin_amdgcn_mfma_f32_16x16x32_f16(af1, bf, acc[1][j], 0, 0, 0);
        }
    }
#undef LOADG

    // Epilogue. D layout: col = lane&15, row = (lane>>4)*4 + r.
    #pragma unroll
    for (int i = 0; i < 2; ++i) {
        const int rbase = m0 + wid * 32 + i * 16 + (lane >> 4) * 4;
        #pragma unroll
        for (int j = 0; j < 8; ++j) {
            const int col = n0b * 128 + j * 16 + (lane & 15);
            const float bv = bias[col];
            #pragma unroll
            for (int r = 0; r < 4; ++r) {
                const int row = rbase + r;
                float v = acc[i][j][r] + bv;
                if (RESID) v = elu1(v) + A[(size_t)row * DDIM + col];
                C[(size_t)row * N + col] = v;
            }
        }
    }
}

extern "C" void kernel_launch(void* const* d_in, const int* in_sizes, int n_in,
                              void* d_out, int out_size, void* d_ws, size_t ws_size,
                              hipStream_t stream) {
    const float* X          = (const float*)d_in[0];
    const int*   edge_index = (const int*)d_in[1];
    const int*   batch_vec  = (const int*)d_in[2];
    const int*   ptrv       = (const int*)d_in[3];
    const int*   sl         = (const int*)d_in[4];
    const int*   sr         = (const int*)d_in[5];
    const float* elem       = (const float*)d_in[6];
    const float* emb        = (const float*)d_in[7];
    const float* stat       = (const float*)d_in[8];
    const float* Wd         = (const float*)d_in[9];
    const float* bd         = (const float*)d_in[10];
    const float* Wo         = (const float*)d_in[11];
    const float* bo         = (const float*)d_in[12];
    float* out = (float*)d_out;

    // ws layout: [W16 square x3 | W16 out | h ping-pong buffers]
    const size_t LW  = (size_t)KT * 10 * 8 * 1024;
    const size_t LWo = (size_t)KT * 4  * 8 * 1024;
    _Float16* W16d = (_Float16*)d_ws;
    _Float16* W16o = (_Float16*)((char*)d_ws + 3 * LW);
    char* hbase = (char*)d_ws + 3 * LW + LWo;
    const size_t rem = ws_size - (3 * LW + LWo);

    int CH = EE;
    while (CH > 128 && (size_t)2 * CH * DDIM * sizeof(float) > rem) CH >>= 1;
    float* buf0 = (float*)hbase;
    float* buf1 = buf0 + (size_t)CH * DDIM;

    for (int l = 0; l < 3; ++l)
        wconv_kernel<<<800, 256, 0, stream>>>(
            Wd + (size_t)l * DDIM * DDIM, W16d + (size_t)l * (LW / 2), DDIM, 10);
    wconv_kernel<<<320, 256, 0, stream>>>(Wo, W16o, OUTD, 4);

    for (int e0 = 0; e0 < EE; e0 += CH) {
        feats4_kernel<<<CH / 4, 256, 0, stream>>>(
            X, edge_index + e0, edge_index + EE + e0, batch_vec, ptrv,
            sl + (size_t)e0 * KK, sr + (size_t)e0 * KK,
            elem + (size_t)e0 * 24, emb + (size_t)e0 * 200,
            stat + (size_t)e0 * 32, buf0);

        dim3 gd(10, CH / 128);
        mfma_gemm_kernel<true><<<gd, 256, 0, stream>>>(
            buf0, W16d + 0 * (LW / 2), bd + 0 * DDIM, buf1, DDIM, 10);
        mfma_gemm_kernel<true><<<gd, 256, 0, stream>>>(
            buf1, W16d + 1 * (LW / 2), bd + 1 * DDIM, buf0, DDIM, 10);
        mfma_gemm_kernel<true><<<gd, 256, 0, stream>>>(
            buf0, W16d + 2 * (LW / 2), bd + 2 * DDIM, buf1, DDIM, 10);

        dim3 go(4, CH / 128);
        mfma_gemm_kernel<false><<<go, 256, 0, stream>>>(
            buf1, W16o, bo, out + (size_t)e0 * OUTD, OUTD, 4);
    }
}

// Round 6
// 1107.648 us; speedup vs baseline: 4.0991x; 1.0278x over previous
//
#include <hip/hip_runtime.h>
#include <math.h>

#define NN   65536
#define EE   32768
#define HH   256
#define KK   24
#define DDIM 1280
#define OUTD 512
#define KT   (DDIM / 32)   // 40 K-steps of 32
#define GCAP 1024          // per-graph edge bucket capacity (mean 512, 23 sigma)

typedef _Float16 half8 __attribute__((ext_vector_type(8)));
typedef float    f32x4 __attribute__((ext_vector_type(4)));

__device__ __forceinline__ float elu1(float x) {
    return x > 0.f ? x : expm1f(x);
}

// ---------------------------------------------------------------------------
// Weight conversion: fp32 row-major W[K][N] -> fp16 fragment-major subtiles.
// ---------------------------------------------------------------------------
__global__ __launch_bounds__(256) void wconv_kernel(
    const float* __restrict__ W, _Float16* __restrict__ W16, int N, int nbN)
{
    const int t    = threadIdx.x;
    const int s    = blockIdx.x * 4 + (t >> 6);
    const int lane = t & 63;
    const int nt = s & 7;
    const int nb = (s >> 3) % nbN;
    const int kt = s / (8 * nbN);
    const int kbase = kt * 32 + 8 * (lane >> 4);
    const int n     = nb * 128 + nt * 16 + (lane & 15);
    half8 v;
    #pragma unroll
    for (int j = 0; j < 8; ++j)
        v[j] = (_Float16)W[(size_t)(kbase + j) * N + n];
    *((half8*)W16 + (size_t)s * 64 + lane) = v;
}

// ---------------------------------------------------------------------------
// Edge bucketing by graph: perm[g*GCAP + i] = local edge id (or -1).
// Scatter order via atomics is nondeterministic but the per-edge OUTPUT is
// order-independent, so the launch stays deterministic where it matters.
// ---------------------------------------------------------------------------
__global__ __launch_bounds__(256) void bucket_init_kernel(int* __restrict__ perm,
                                                          int* __restrict__ cnt)
{
    const int i = blockIdx.x * 256 + threadIdx.x;      // 16384 int4 = 64*GCAP ints
    ((int4*)perm)[i] = make_int4(-1, -1, -1, -1);
    if (blockIdx.x == 0 && threadIdx.x < 64) cnt[threadIdx.x] = 0;
}

__global__ __launch_bounds__(256) void bucket_scatter_kernel(
    const int* __restrict__ src_idx, const int* __restrict__ batch_vec,
    int* __restrict__ perm, int* __restrict__ cnt, int nE)
{
    const int e = blockIdx.x * 256 + threadIdx.x;
    if (e >= nE) return;
    const int g = batch_vec[src_idx[e]];
    const int idx = atomicAdd(&cnt[g], 1);
    perm[g * GCAP + idx] = e;
}

// ---------------------------------------------------------------------------
// Feature assembly, graph-bucketed: block b -> XCD b&7 -> graphs g==b&7 mod 8,
// so each graph's 1 MB X-slice stays resident in one XCD's 4 MB L2 across its
// ~24x-reused pooled gathers. One wave per edge, float4 per lane, branchless
// pooling (mask applies AFTER ptr offset, matching reference semantics).
// ---------------------------------------------------------------------------
__global__ __launch_bounds__(256) void feats4_kernel(
    const float* __restrict__ X, const int* __restrict__ perm,
    const int* __restrict__ src_idx, const int* __restrict__ dst_idx,
    const int* __restrict__ ptrv,
    const int* __restrict__ sl, const int* __restrict__ sr,
    const float* __restrict__ elem, const float* __restrict__ emb,
    const float* __restrict__ stat, float* __restrict__ F)
{
    const int b  = blockIdx.x;                 // 0..16383
    const int x  = b & 7;
    const int j  = b >> 3;                     // 0..2047
    const int g  = x + 8 * (j >> 8);           // graph id, all blocks of g on XCD x
    const int jj = j & 255;                    // block within graph
    const int e  = perm[g * GCAP + jj * 4 + (threadIdx.x >> 6)];
    if (e < 0) return;

    const int lane = threadIdx.x & 63;
    const int src  = src_idx[e];
    const int dst  = dst_idx[e];
    const int off  = ptrv[g];

    const float4* X4 = (const float4*)X;
    float4* f4 = (float4*)(F + (size_t)e * DDIM);

    f4[lane]      = X4[(size_t)src * 64 + lane];
    f4[64 + lane] = X4[(size_t)dst * 64 + lane];

    float4 sL = make_float4(0.f, 0.f, 0.f, 0.f);
    float4 sR = make_float4(0.f, 0.f, 0.f, 0.f);
    int cL = 0, cR = 0;
    #pragma unroll
    for (int k = 0; k < KK; ++k) {
        const int il  = sl[e * KK + k] + off;
        const int ir  = sr[e * KK + k] + off;
        const int okL = il >= 0;
        const int okR = ir >= 0;
        const float wL = okL ? 1.f : 0.f;
        const float wR = okR ? 1.f : 0.f;
        const float4 vl = X4[(size_t)(okL ? il : 0) * 64 + lane];
        const float4 vr = X4[(size_t)(okR ? ir : 0) * 64 + lane];
        sL.x += vl.x * wL; sL.y += vl.y * wL; sL.z += vl.z * wL; sL.w += vl.w * wL;
        sR.x += vr.x * wR; sR.y += vr.y * wR; sR.z += vr.z * wR; sR.w += vr.w * wR;
        cL += okL; cR += okR;
    }
    const float rL = cL > 0 ? 1.f / (float)cL : 0.f;
    const float rR = cR > 0 ? 1.f / (float)cR : 0.f;
    f4[128 + lane] = make_float4(sL.x * rL, sL.y * rL, sL.z * rL, sL.w * rL);
    f4[192 + lane] = make_float4(sR.x * rR, sR.y * rR, sR.z * rR, sR.w * rR);

    if (lane < 6)       f4[256 + lane] = ((const float4*)(elem + (size_t)e * 24))[lane];
    else if (lane < 56) f4[256 + lane] = ((const float4*)(emb  + (size_t)e * 200))[lane - 6];
    else                f4[256 + lane] = ((const float4*)(stat + (size_t)e * 32))[lane - 56];
}

// ---------------------------------------------------------------------------
// MFMA GEMM (unchanged from R5): 128x128 tile, BK=32, mfma_f32_16x16x32_f16,
// fp32 accum, XCD-affinity swizzle keeping each m-tile's A panel in one L2.
// ---------------------------------------------------------------------------
template<bool RESID>
__global__ __launch_bounds__(256) void mfma_gemm_kernel(
    const float* __restrict__ A, const _Float16* __restrict__ W16,
    const float* __restrict__ bias, float* __restrict__ C,
    int N, int nbN)
{
    __shared__ __align__(16) char sA[8192];
    __shared__ __align__(16) char sB[8192];

    const int t    = threadIdx.x;
    const int wid  = t >> 6;
    const int lane = t & 63;

    int m_t, n_t;
    if ((gridDim.y & 7) == 0) {
        const int flat = blockIdx.y * gridDim.x + blockIdx.x;
        m_t = (flat & 7) + 8 * (flat / (8 * gridDim.x));
        n_t = (flat >> 3) % gridDim.x;
    } else {
        m_t = blockIdx.y;
        n_t = blockIdx.x;
    }
    const int m0  = m_t * 128;
    const int n0b = n_t;

    f32x4 acc[2][8];
    #pragma unroll
    for (int i = 0; i < 2; ++i)
        #pragma unroll
        for (int j = 0; j < 8; ++j)
            acc[i][j] = (f32x4){0.f, 0.f, 0.f, 0.f};

    const int ar  = t >> 1;
    const int akh = (t & 1) * 16;
    const float* Ag = A + (size_t)(m0 + ar) * DDIM + akh;
    char* aw = sA + ((ar >> 4) * 1024) + (((ar & 15) + 2 * akh) * 16);

    const int bs    = t >> 5;
    const int bslot = t & 31;
    const char* W16b = (const char*)W16;
    char* bw = sB + bs * 1024 + bslot * 32;

    float4 a0, a1, a2, a3;
    uint4  b0, b1;

#define LOADG(ktv)                                                              \
    {                                                                           \
        const float4* ap = (const float4*)(Ag + (size_t)(ktv) * 32);            \
        a0 = ap[0]; a1 = ap[1]; a2 = ap[2]; a3 = ap[3];                         \
        const uint4* bp = (const uint4*)(W16b +                                 \
            ((size_t)((ktv) * nbN + n0b) * 8 + bs) * 1024 + bslot * 32);        \
        b0 = bp[0]; b1 = bp[1];                                                 \
    }

    LOADG(0);

    for (int kt = 0; kt < KT; ++kt) {
        __syncthreads();

        half8 h0, h1;
        h0[0]=(_Float16)a0.x; h0[1]=(_Float16)a0.y; h0[2]=(_Float16)a0.z; h0[3]=(_Float16)a0.w;
        h0[4]=(_Float16)a1.x; h0[5]=(_Float16)a1.y; h0[6]=(_Float16)a1.z; h0[7]=(_Float16)a1.w;
        h1[0]=(_Float16)a2.x; h1[1]=(_Float16)a2.y; h1[2]=(_Float16)a2.z; h1[3]=(_Float16)a2.w;
        h1[4]=(_Float16)a3.x; h1[5]=(_Float16)a3.y; h1[6]=(_Float16)a3.z; h1[7]=(_Float16)a3.w;
        *(half8*)aw         = h0;
        *(half8*)(aw + 256) = h1;
        *(uint4*)bw        = b0;
        *(uint4*)(bw + 16) = b1;

        __syncthreads();

        if (kt + 1 < KT) LOADG(kt + 1);

        const half8* pa = (const half8*)sA;
        const half8* pb = (const half8*)sB;
        const half8 af0 = pa[(2 * wid)     * 64 + lane];
        const half8 af1 = pa[(2 * wid + 1) * 64 + lane];
        #pragma unroll
        for (int j = 0; j < 8; ++j) {
            const half8 bf = pb[j * 64 + lane];
            acc[0][j] = __builtin_amdgcn_mfma_f32_16x16x32_f16(af0, bf, acc[0][j], 0, 0, 0);
            acc[1][j] = __builtin_amdgcn_mfma_f32_16x16x32_f16(af1, bf, acc[1][j], 0, 0, 0);
        }
    }
#undef LOADG

    #pragma unroll
    for (int i = 0; i < 2; ++i) {
        const int rbase = m0 + wid * 32 + i * 16 + (lane >> 4) * 4;
        #pragma unroll
        for (int j = 0; j < 8; ++j) {
            const int col = n0b * 128 + j * 16 + (lane & 15);
            const float bv = bias[col];
            #pragma unroll
            for (int r = 0; r < 4; ++r) {
                const int row = rbase + r;
                float v = acc[i][j][r] + bv;
                if (RESID) v = elu1(v) + A[(size_t)row * DDIM + col];
                C[(size_t)row * N + col] = v;
            }
        }
    }
}

extern "C" void kernel_launch(void* const* d_in, const int* in_sizes, int n_in,
                              void* d_out, int out_size, void* d_ws, size_t ws_size,
                              hipStream_t stream) {
    const float* X          = (const float*)d_in[0];
    const int*   edge_index = (const int*)d_in[1];
    const int*   batch_vec  = (const int*)d_in[2];
    const int*   ptrv       = (const int*)d_in[3];
    const int*   sl         = (const int*)d_in[4];
    const int*   sr         = (const int*)d_in[5];
    const float* elem       = (const float*)d_in[6];
    const float* emb        = (const float*)d_in[7];
    const float* stat       = (const float*)d_in[8];
    const float* Wd         = (const float*)d_in[9];
    const float* bd         = (const float*)d_in[10];
    const float* Wo         = (const float*)d_in[11];
    const float* bo         = (const float*)d_in[12];
    float* out = (float*)d_out;

    // ws layout: [W16 square x3 | W16 out | perm 64*GCAP | cnt 64 | h ping-pong]
    const size_t LW  = (size_t)KT * 10 * 8 * 1024;
    const size_t LWo = (size_t)KT * 4  * 8 * 1024;
    _Float16* W16d = (_Float16*)d_ws;
    _Float16* W16o = (_Float16*)((char*)d_ws + 3 * LW);
    int* perm = (int*)((char*)d_ws + 3 * LW + LWo);
    int* cnt  = perm + 64 * GCAP;
    char* hbase = (char*)(cnt + 64);
    const size_t used = (size_t)((char*)hbase - (char*)d_ws);
    const size_t rem = ws_size - used;

    int CH = EE;
    while (CH > 128 && (size_t)2 * CH * DDIM * sizeof(float) > rem) CH >>= 1;
    float* buf0 = (float*)hbase;
    float* buf1 = buf0 + (size_t)CH * DDIM;

    for (int l = 0; l < 3; ++l)
        wconv_kernel<<<800, 256, 0, stream>>>(
            Wd + (size_t)l * DDIM * DDIM, W16d + (size_t)l * (LW / 2), DDIM, 10);
    wconv_kernel<<<320, 256, 0, stream>>>(Wo, W16o, OUTD, 4);

    for (int e0 = 0; e0 < EE; e0 += CH) {
        // bucket this chunk's edges by graph
        bucket_init_kernel<<<64, 256, 0, stream>>>(perm, cnt);
        bucket_scatter_kernel<<<(CH + 255) / 256, 256, 0, stream>>>(
            edge_index + e0, batch_vec, perm, cnt, CH);

        feats4_kernel<<<64 * (GCAP / 4), 256, 0, stream>>>(
            X, perm, edge_index + e0, edge_index + EE + e0, ptrv,
            sl + (size_t)e0 * KK, sr + (size_t)e0 * KK,
            elem + (size_t)e0 * 24, emb + (size_t)e0 * 200,
            stat + (size_t)e0 * 32, buf0);

        dim3 gd(10, CH / 128);
        mfma_gemm_kernel<true><<<gd, 256, 0, stream>>>(
            buf0, W16d + 0 * (LW / 2), bd + 0 * DDIM, buf1, DDIM, 10);
        mfma_gemm_kernel<true><<<gd, 256, 0, stream>>>(
            buf1, W16d + 1 * (LW / 2), bd + 1 * DDIM, buf0, DDIM, 10);
        mfma_gemm_kernel<true><<<gd, 256, 0, stream>>>(
            buf0, W16d + 2 * (LW / 2), bd + 2 * DDIM, buf1, DDIM, 10);

        dim3 go(4, CH / 128);
        mfma_gemm_kernel<false><<<go, 256, 0, stream>>>(
            buf1, W16o, bo, out + (size_t)e0 * OUTD, OUTD, 4);
    }
}